// Round 3
// baseline (319.213 us; speedup 1.0000x reference)
//
#include <hip/hip_runtime.h>
#include <hip/hip_bf16.h>
#include <stdint.h>

#define ALPHA 0.2f

typedef __attribute__((ext_vector_type(4))) float f32x4;
typedef __attribute__((ext_vector_type(8))) __bf16 bf16x8;
typedef __attribute__((ext_vector_type(4))) __bf16 bf16x4;
typedef __attribute__((ext_vector_type(8))) unsigned short u16x8;

static __device__ __forceinline__ float bf2f(unsigned short h) {
  unsigned u = ((unsigned)h) << 16;
  return __builtin_bit_cast(float, u);
}
// monotone float<->uint map for atomicMax on floats
static __device__ __forceinline__ unsigned fmap(float f) {
  unsigned u = __builtin_bit_cast(unsigned, f);
  return (u & 0x80000000u) ? ~u : (u | 0x80000000u);
}
static __device__ __forceinline__ float funmap(unsigned m) {
  unsigned u = (m & 0x80000000u) ? (m ^ 0x80000000u) : ~m;
  return __builtin_bit_cast(float, u);
}
// async global->LDS, 16B per lane. LDS dest must be wave-uniform base + lane*16.
static __device__ __forceinline__ void gl_lds16(const void* g, void* lds) {
  __builtin_amdgcn_global_load_lds(
      (const __attribute__((address_space(1))) unsigned int*)g,
      (__attribute__((address_space(3))) unsigned int*)lds, 16, 0, 0);
}

// ---------------- adj -> bitmask (2 MB); one block per row ----------------
__global__ void __launch_bounds__(256) k_pack_bits(const int* __restrict__ adj,
                                                   unsigned int* __restrict__ bits) {
  int i = blockIdx.x;
  int lane = threadIdx.x & 63, wid = threadIdx.x >> 6;
#pragma unroll 4
  for (int it = 0; it < 16; ++it) {
    int j = it * 256 + wid * 64 + lane;
    unsigned long long m = __ballot(adj[(size_t)i * 4096 + j] != 0);
    if (lane == 0) {
      int w64 = it * 4 + wid;
      bits[i * 128 + 2 * w64]     = (unsigned int)m;
      bits[i * 128 + 2 * w64 + 1] = (unsigned int)(m >> 32);
    }
  }
}

// ---------------- transpose + cast: in [K][N] fp32 -> out [N][K] bf16 ----------------
__global__ void k_transpose_bf16(const float* __restrict__ in, unsigned short* __restrict__ out,
                                 int K, int N) {
  __shared__ float t[32][33];
  long bs = (long)K * N;
  const float* inb = in + blockIdx.z * bs;
  unsigned short* outb = out + blockIdx.z * bs;
  int k0 = blockIdx.x * 32, n0 = blockIdx.y * 32;
  int tx = threadIdx.x & 31, ty = threadIdx.x >> 5;
#pragma unroll
  for (int it = 0; it < 4; ++it)
    t[ty + it * 8][tx] = inb[(long)(k0 + ty + it * 8) * N + n0 + tx];
  __syncthreads();
#pragma unroll
  for (int it = 0; it < 4; ++it) {
    float v = t[tx][ty + it * 8];
    outb[(long)(n0 + ty + it * 8) * K + k0 + tx] = __builtin_bit_cast(unsigned short, (__bf16)v);
  }
}

// ---------------- wa = W @ a halves: one wave per input row (+ dmax zero) ----------------
__global__ void k_wa(const float* __restrict__ W, const float* __restrict__ a,
                     float* __restrict__ wa, int headK, int F, unsigned* dz) {
  if (dz && blockIdx.x == 0 && threadIdx.x < 8) dz[threadIdx.x] = 0;
  int w = (blockIdx.x * blockDim.x + threadIdx.x) >> 6;
  int lane = threadIdx.x & 63;
  int h = w / headK, fl = w % headK;
  const float* row = W + (size_t)w * F;
  const float* ah = a + (size_t)h * 2 * F;
  float s0 = 0.f, s1 = 0.f;
  for (int fo = lane; fo < F; fo += 64) {
    float wv = row[fo];
    s0 += wv * ah[fo];
    s1 += wv * ah[F + fo];
  }
#pragma unroll
  for (int off = 32; off; off >>= 1) {
    s0 += __shfl_xor(s0, off);
    s1 += __shfl_xor(s1, off);
  }
  if (lane == 0) {
    wa[(size_t)(h * 2 + 0) * headK + fl] = s0;
    wa[(size_t)(h * 2 + 1) * headK + fl] = s1;
  }
}

// ---------------- layer1 matvec + x cast + dmax, fused ----------------
// grid 256: each wave 4 rows. Reads fp32 x, writes bf16 xb, src/dst per head, atomic dmax.
__global__ void __launch_bounds__(256)
k_matvec1(const float* __restrict__ x, const float* __restrict__ wa,
          unsigned short* __restrict__ xb, float* __restrict__ srcv,
          float* __restrict__ dstv, unsigned* __restrict__ dmaxU) {
  int lane = threadIdx.x & 63, wid = threadIdx.x >> 6;
  float wv[8][8];
#pragma unroll
  for (int v = 0; v < 8; ++v)
#pragma unroll
    for (int j = 0; j < 8; ++j) wv[v][j] = wa[v * 512 + lane * 8 + j];
  int base = (blockIdx.x * 4 + wid) * 4;
  float wmax[4] = {-1e30f, -1e30f, -1e30f, -1e30f};
  for (int rr = 0; rr < 4; ++rr) {
    int i = base + rr;
    const f32x4* xp = (const f32x4*)(x + (size_t)i * 512 + lane * 8);
    f32x4 x0 = xp[0], x1 = xp[1];
    float xf[8];
#pragma unroll
    for (int j = 0; j < 4; ++j) { xf[j] = x0[j]; xf[j + 4] = x1[j]; }
    bf16x8 xbv;
#pragma unroll
    for (int j = 0; j < 8; ++j) xbv[j] = (__bf16)xf[j];
    *(bf16x8*)(xb + (size_t)i * 512 + lane * 8) = xbv;
    float s[8] = {};
#pragma unroll
    for (int v = 0; v < 8; ++v)
#pragma unroll
      for (int j = 0; j < 8; ++j) s[v] += xf[j] * wv[v][j];
#pragma unroll
    for (int v = 0; v < 8; ++v)
#pragma unroll
      for (int off = 32; off; off >>= 1) s[v] += __shfl_xor(s[v], off);
    if (lane == 0) {
#pragma unroll
      for (int h = 0; h < 4; ++h) {
        srcv[h * 4096 + i] = s[h * 2];
        dstv[h * 4096 + i] = s[h * 2 + 1];
      }
    }
#pragma unroll
    for (int h = 0; h < 4; ++h) wmax[h] = fmaxf(wmax[h], s[h * 2 + 1]);
  }
  if (lane == 0) {
#pragma unroll
    for (int h = 0; h < 4; ++h) atomicMax(&dmaxU[h], fmap(wmax[h]));
  }
}

// ---------------- layer2 matvec + dmax, fused; grid 256 ----------------
__global__ void __launch_bounds__(256)
k_matvec2(const unsigned short* __restrict__ h1, const float* __restrict__ wa,
          float* __restrict__ srcv, float* __restrict__ dstv, unsigned* __restrict__ dmaxU) {
  int lane = threadIdx.x & 63, wid = threadIdx.x >> 6;
  float wv[2][16];
#pragma unroll
  for (int v = 0; v < 2; ++v)
#pragma unroll
    for (int j = 0; j < 16; ++j) wv[v][j] = wa[v * 1024 + lane * 16 + j];
  int base = (blockIdx.x * 4 + wid) * 4;
  float wmax = -1e30f;
  for (int rr = 0; rr < 4; ++rr) {
    int i = base + rr;
    u16x8 x0 = *(const u16x8*)(h1 + (size_t)i * 1024 + lane * 16);
    u16x8 x1 = *(const u16x8*)(h1 + (size_t)i * 1024 + lane * 16 + 8);
    float s0 = 0.f, s1 = 0.f;
#pragma unroll
    for (int j = 0; j < 8; ++j) {
      float a0 = bf2f(x0[j]), a1 = bf2f(x1[j]);
      s0 += a0 * wv[0][j] + a1 * wv[0][j + 8];
      s1 += a0 * wv[1][j] + a1 * wv[1][j + 8];
    }
#pragma unroll
    for (int off = 32; off; off >>= 1) {
      s0 += __shfl_xor(s0, off);
      s1 += __shfl_xor(s1, off);
    }
    if (lane == 0) { srcv[i] = s0; dstv[i] = s1; }
    wmax = fmaxf(wmax, s1);
  }
  if (lane == 0) atomicMax(&dmaxU[0], fmap(wmax));
}

// ---------------- Wh GEMM: A[4096,K]bf16 @ BT[f][K]bf16 -> whT[f][4096] bf16 ----------------
// NI = f-frags per wave; tile 64 x (NI*32). 4 waves (2m x 2n).
template <int NI>
__global__ void __launch_bounds__(256, 4)
k_gemm_wh(const unsigned short* __restrict__ A, const unsigned short* __restrict__ BT,
          unsigned short* __restrict__ whT, int K) {
  constexpr int NT = NI * 32;
  __shared__ unsigned short As[64 * 32];
  __shared__ unsigned short Bs[NT * 32];
  const int tid = threadIdx.x, lane = tid & 63, wid = tid >> 6;
  const int q = lane >> 4, l15 = lane & 15;
  const int i0 = blockIdx.x * 64;
  const int fbase = blockIdx.z * 256 + blockIdx.y * NT;
  const int wm = wid >> 1, wn = wid & 1;
  f32x4 acc[2][NI] = {};
  const unsigned short* aRow = A + (long)(i0 + (tid >> 2)) * K + (tid & 3) * 8;
  for (int kk = 0; kk < K; kk += 32) {
    __syncthreads();
    gl_lds16(aRow + kk, (char*)As + tid * 16);
#pragma unroll
    for (int c = tid; c < NT * 4; c += 256)
      gl_lds16(BT + (long)(fbase + (c >> 2)) * K + kk + (c & 3) * 8, (char*)Bs + c * 16);
    __syncthreads();
    bf16x8 af[2], bfr[NI];
#pragma unroll
    for (int mi = 0; mi < 2; ++mi)
      af[mi] = *(const bf16x8*)&As[(wm * 32 + mi * 16 + l15) * 32 + q * 8];
#pragma unroll
    for (int ni = 0; ni < NI; ++ni)
      bfr[ni] = *(const bf16x8*)&Bs[(wn * (NI * 16) + ni * 16 + l15) * 32 + q * 8];
#pragma unroll
    for (int mi = 0; mi < 2; ++mi)
#pragma unroll
      for (int ni = 0; ni < NI; ++ni)
        acc[mi][ni] = __builtin_amdgcn_mfma_f32_16x16x32_bf16(af[mi], bfr[ni], acc[mi][ni], 0, 0, 0);
  }
#pragma unroll
  for (int mi = 0; mi < 2; ++mi)
#pragma unroll
    for (int ni = 0; ni < NI; ++ni) {
      int ig = i0 + wm * 32 + mi * 16 + q * 4;
      int fg = fbase + wn * (NI * 16) + ni * 16 + l15;
      bf16x4 v;
#pragma unroll
      for (int r = 0; r < 4; ++r) v[r] = (__bf16)acc[mi][ni][r];
      *(bf16x4*)&whT[(long)fg * 4096 + ig] = v;
    }
}

// ---------------- fused attention GEMM, j-split, fixed-shift softmax ----------------
// block 256 (4 waves): 64 rows x 256 f, j-step 64.
template <int JS, int H, int OC>
__global__ void __launch_bounds__(256, 2)
k_attn2(const unsigned short* __restrict__ whT, const unsigned int* __restrict__ bits,
        const float* __restrict__ srcv, const float* __restrict__ dstv,
        const unsigned* __restrict__ dmaxU, float* __restrict__ Opart,
        float* __restrict__ Lpart) {
  __shared__ unsigned short Bs[256 * 64];  // [f][64k], k-chunks XOR-swizzled
  __shared__ unsigned short Ps[64 * 72];   // [row][64k + 8 pad]
  __shared__ float Lred[4][64];
  const int tid = threadIdx.x, lane = tid & 63, wid = tid >> 6;
  const int q = lane >> 4, l15 = lane & 15;
  const int bid = blockIdx.x;
  const int g = bid % (H * JS);
  const int head = g % H;
  const int js = g / H;
  const int i0 = (bid / (H * JS)) * 64;
  const int st0 = (64 * js) / JS, st1 = (64 * (js + 1)) / JS;

  const float* srcp = srcv + head * 4096;
  const float* dstp = dstv + head * 4096;
  const unsigned short* wh_head = whT + (size_t)head * 256 * 4096;

  const int prow = tid & 63, kq = tid >> 6;
  float src_r = srcp[i0 + prow];
  float m_r;
  {
    float xm = src_r + funmap(dmaxU[head]);
    m_r = fmaxf(xm, ALPHA * xm);
  }
  const unsigned int* brow = bits + (size_t)(i0 + prow) * 128;
  float lsum = 0.f;
  f32x4 acc[4][4] = {};

  for (int jstep = st0; jstep < st1; ++jstep) {
    int j0 = jstep * 64;
    __syncthreads();
    // stage B: 256 f x 64 k = 32 KB, XOR-swizzled 16B chunks (slot = c ^ (f&7))
#pragma unroll
    for (int it = 0; it < 8; ++it) {
      int cid = it * 256 + tid;
      int row = cid >> 3, slot = cid & 7;
      int c = slot ^ (row & 7);
      gl_lds16(wh_head + (size_t)row * 4096 + j0 + c * 8, (char*)Bs + cid * 16);
    }
    // P-gen: thread (prow, kq) covers 16 j at j0 + kq*16
    {
      int jw = j0 + kq * 16;
      f32x4 dz[4];
#pragma unroll
      for (int c4 = 0; c4 < 4; ++c4) dz[c4] = *(const f32x4*)(dstp + jw + c4 * 4);
      unsigned wb = (brow[(j0 >> 5) + (kq >> 1)] >> ((kq & 1) * 16)) & 0xFFFFu;
#pragma unroll
      for (int c8 = 0; c8 < 2; ++c8) {
        bf16x8 pv;
#pragma unroll
        for (int jj = 0; jj < 8; ++jj) {
          float dj = dz[c8 * 2 + (jj >> 2)][jj & 3];
          float e = src_r + dj;
          e = fmaxf(e, ALPHA * e);
          float pe = ((wb >> (c8 * 8 + jj)) & 1u) ? __expf(e - m_r) : 0.f;
          lsum += pe;
          pv[jj] = (__bf16)pe;
        }
        *(bf16x8*)&Ps[prow * 72 + kq * 16 + c8 * 8] = pv;
      }
    }
    __syncthreads();
#pragma unroll
    for (int s = 0; s < 2; ++s) {
      bf16x8 af[4], bfr[4];
#pragma unroll
      for (int mi = 0; mi < 4; ++mi)
        af[mi] = *(const bf16x8*)&Ps[(mi * 16 + l15) * 72 + s * 32 + q * 8];
#pragma unroll
      for (int ni = 0; ni < 4; ++ni) {
        int f = wid * 64 + ni * 16 + l15;
        int slot = (s * 4 + q) ^ (l15 & 7);
        bfr[ni] = *(const bf16x8*)&Bs[f * 64 + slot * 8];
      }
#pragma unroll
      for (int mi = 0; mi < 4; ++mi)
#pragma unroll
        for (int ni = 0; ni < 4; ++ni)
          acc[mi][ni] = __builtin_amdgcn_mfma_f32_16x16x32_bf16(af[mi], bfr[ni], acc[mi][ni], 0, 0, 0);
    }
  }
  // epilogue: row-sum partials + unnormalized O partials
  __syncthreads();
  Lred[kq][prow] = lsum;
  __syncthreads();
  if (tid < 64)
    Lpart[(size_t)(js * H + head) * 4096 + i0 + tid] =
        Lred[0][tid] + Lred[1][tid] + Lred[2][tid] + Lred[3][tid];
  float* Ob = Opart + (size_t)js * 4096 * OC + head * 256;
#pragma unroll
  for (int mi = 0; mi < 4; ++mi)
#pragma unroll
    for (int ni = 0; ni < 4; ++ni) {
      int i = i0 + mi * 16 + q * 4;
      int col = wid * 64 + ni * 16 + l15;
#pragma unroll
      for (int r = 0; r < 4; ++r)
        Ob[(size_t)(i + r) * OC + col] = acc[mi][ni][r];
    }
}

// ---------------- combine layer1: h1 = ELU((sum Op)/l) as bf16 ----------------
__global__ void __launch_bounds__(256) k_comb1(const float* __restrict__ Op,
                                               const float* __restrict__ Lp,
                                               unsigned short* __restrict__ h1, int JS) {
  int gidx = blockIdx.x * 256 + threadIdx.x;
  int i = gidx >> 8, c0 = (gidx & 255) * 4;
  int h = c0 >> 8;
  float l = 0.f;
  for (int js = 0; js < JS; ++js) l += Lp[(js * 4 + h) * 4096 + i];
  float inv = 1.f / l;
  f32x4 s = {0.f, 0.f, 0.f, 0.f};
  for (int js = 0; js < JS; ++js)
    s += *(const f32x4*)(Op + (size_t)js * 4096 * 1024 + (size_t)i * 1024 + c0);
  bf16x4 o;
#pragma unroll
  for (int r = 0; r < 4; ++r) {
    float v = s[r] * inv;
    v = v > 0.f ? v : (__expf(v) - 1.f);
    o[r] = (__bf16)v;
  }
  *(bf16x4*)(h1 + (size_t)i * 1024 + c0) = o;
}

// ---------------- combine layer2: out = (sum Op_js)/l, fp32 ----------------
__global__ void __launch_bounds__(256) k_comb2(const float* __restrict__ Op,
                                               const float* __restrict__ Lp,
                                               float* __restrict__ out, int JS) {
  int gidx = blockIdx.x * 256 + threadIdx.x;
  int i = gidx >> 6, c0 = (gidx & 63) * 4;
  float l = 0.f;
  for (int js = 0; js < JS; ++js) l += Lp[js * 4096 + i];
  f32x4 s = {0.f, 0.f, 0.f, 0.f};
  for (int js = 0; js < JS; ++js)
    s += *(const f32x4*)(Op + (size_t)js * 4096 * 256 + (size_t)i * 256 + c0);
  float inv = 1.f / l;
  f32x4 o;
#pragma unroll
  for (int r = 0; r < 4; ++r) o[r] = s[r] * inv;
  *(f32x4*)(out + (size_t)i * 256 + c0) = o;
}

extern "C" void kernel_launch(void* const* d_in, const int* in_sizes, int n_in,
                              void* d_out, int out_size, void* d_ws, size_t ws_size,
                              hipStream_t stream) {
  const float* x  = (const float*)d_in[0];
  const int* adj  = (const int*)d_in[1];
  const float* W1 = (const float*)d_in[2];
  const float* a1 = (const float*)d_in[3];
  const float* W2 = (const float*)d_in[4];
  const float* a2 = (const float*)d_in[5];

  char* ws = (char*)d_ws;
  size_t off = 0;
  auto alloc = [&](size_t bytes) {
    void* p = ws + off;
    off = (off + bytes + 255) & ~(size_t)255;
    return p;
  };
  unsigned int*   bits = (unsigned int*)  alloc((size_t)4096 * 128 * 4);    //  2 MB
  unsigned short* xb   = (unsigned short*)alloc((size_t)4096 * 512 * 2);    //  4 MB
  unsigned short* w1t  = (unsigned short*)alloc((size_t)4 * 256 * 512 * 2); //  1 MB
  unsigned short* w2t  = (unsigned short*)alloc((size_t)256 * 1024 * 2);    // .5 MB
  unsigned short* whT1 = (unsigned short*)alloc((size_t)1024 * 4096 * 2);   //  8 MB
  unsigned short* h1   = (unsigned short*)alloc((size_t)4096 * 1024 * 2);   //  8 MB
  unsigned short* whT2 = (unsigned short*)alloc((size_t)256 * 4096 * 2);    //  2 MB
  float* wa1  = (float*)alloc((size_t)8 * 512 * 4);
  float* wa2  = (float*)alloc((size_t)2 * 1024 * 4);
  float* src1 = (float*)alloc(4 * 4096 * 4);
  float* dst1 = (float*)alloc(4 * 4096 * 4);
  float* src2 = (float*)alloc(4096 * 4);
  float* dst2 = (float*)alloc(4096 * 4);
  unsigned* dmaxU = (unsigned*)alloc(8 * 4);   // [0..3]=L1 heads, [4]=L2
  float* Lp1  = (float*)alloc((size_t)12 * 4096 * 4);
  float* Lp2  = (float*)alloc((size_t)12 * 4096 * 4);
  // big path: JS1=3 (48MB), JS2=12 (48MB, same region); small: JS1=2/JS2=8 (32MB)
  bool big = ws_size >= off + ((size_t)50 << 20);
  float* Opart = (float*)alloc(big ? ((size_t)3 * 4096 * 1024 * 4)
                                   : ((size_t)2 * 4096 * 1024 * 4));

  // prep
  k_pack_bits<<<dim3(4096), dim3(256), 0, stream>>>(adj, bits);
  k_transpose_bf16<<<dim3(16, 8, 4), dim3(256), 0, stream>>>(W1, w1t, 512, 256);
  k_transpose_bf16<<<dim3(32, 8, 1), dim3(256), 0, stream>>>(W2, w2t, 1024, 256);
  k_wa<<<dim3(512), dim3(256), 0, stream>>>(W1, a1, wa1, 512, 256, dmaxU);
  k_wa<<<dim3(256), dim3(256), 0, stream>>>(W2, a2, wa2, 1024, 256, nullptr);

  // layer 1
  k_matvec1<<<dim3(256), dim3(256), 0, stream>>>(x, wa1, xb, src1, dst1, dmaxU);
  k_gemm_wh<4><<<dim3(64, 2, 4), dim3(256), 0, stream>>>(xb, w1t, whT1, 512);
  if (big) {
    k_attn2<3, 4, 1024><<<dim3(768), dim3(256), 0, stream>>>(whT1, bits, src1, dst1, dmaxU, Opart, Lp1);
    k_comb1<<<dim3(4096), dim3(256), 0, stream>>>(Opart, Lp1, h1, 3);
  } else {
    k_attn2<2, 4, 1024><<<dim3(512), dim3(256), 0, stream>>>(whT1, bits, src1, dst1, dmaxU, Opart, Lp1);
    k_comb1<<<dim3(4096), dim3(256), 0, stream>>>(Opart, Lp1, h1, 2);
  }

  // layer 2
  k_matvec2<<<dim3(256), dim3(256), 0, stream>>>(h1, wa2, src2, dst2, dmaxU + 4);
  k_gemm_wh<2><<<dim3(64, 4, 1), dim3(256), 0, stream>>>(h1, w2t, whT2, 1024);
  if (big) {
    k_attn2<12, 1, 256><<<dim3(768), dim3(256), 0, stream>>>(whT2, bits, src2, dst2, dmaxU + 4, Opart, Lp2);
    k_comb2<<<dim3(1024), dim3(256), 0, stream>>>(Opart, Lp2, (float*)d_out, 12);
  } else {
    k_attn2<8, 1, 256><<<dim3(512), dim3(256), 0, stream>>>(whT2, bits, src2, dst2, dmaxU + 4, Opart, Lp2);
    k_comb2<<<dim3(1024), dim3(256), 0, stream>>>(Opart, Lp2, (float*)d_out, 8);
  }
}